// Round 2
// baseline (143.416 us; speedup 1.0000x reference)
//
#include <hip/hip_runtime.h>
#include <hip/hip_bf16.h>
#include <math.h>

#define B_ 8
#define T_ 2048
#define C_ 1024
#define H_ 64
#define M_ (B_*T_)   // 16384 rows

typedef __attribute__((ext_vector_type(8))) short bf16x8;
typedef __attribute__((ext_vector_type(4))) float floatx4;

// fp32 -> bf16 round-to-nearest-even (cold paths)
static __device__ __forceinline__ unsigned short f2bf(float f) {
    union { float f; unsigned u; } v; v.f = f;
    unsigned r = v.u + 0x7fffu + ((v.u >> 16) & 1u);
    return (unsigned short)(r >> 16);
}
// fp32 -> bf16 round-half-up (2 VALU) for hot paths
static __device__ __forceinline__ unsigned short f2bf_fast(float f) {
    union { float f; unsigned u; } v; v.f = f;
    return (unsigned short)((v.u + 0x8000u) >> 16);
}
// pack two fp32 -> bf16 pair [hi|lo] in 3 VALU (add, add, v_perm)
static __device__ __forceinline__ unsigned pk2h(float lo, float hi) {
    union { float f; unsigned u; } a, b; a.f = lo; b.f = hi;
    return __builtin_amdgcn_perm(b.u + 0x8000u, a.u + 0x8000u, 0x07060302u);
}
static __device__ __forceinline__ bf16x8 cvt8(float4 f0, float4 f1) {
    union { uint4 u; bf16x8 v; } r;
    r.u.x = pk2h(f0.x, f0.y); r.u.y = pk2h(f0.z, f0.w);
    r.u.z = pk2h(f1.x, f1.y); r.u.w = pk2h(f1.z, f1.w);
    return r.v;
}
// 2^x
static __device__ __forceinline__ float fexp2(float x) {
#if defined(__has_builtin)
#if __has_builtin(__builtin_amdgcn_exp2f)
    return __builtin_amdgcn_exp2f(x);
#else
    return exp2f(x);
#endif
#else
    return exp2f(x);
#endif
}

#define MFMA(a,b,c) __builtin_amdgcn_mfma_f32_16x16x32_bf16((a),(b),(c),0,0,0)

// ---------------------------------------------------------------------------
// Kernel 0: W prep -> wt2 in MFMA B-fragment order (unchanged).
// wt2 flat: ((tile*32 + kchunk)*64 + lane)*8; tile=0..11 (16 cols, q|k|v),
// kchunk=0..31 (32 k each); lane frag [col=l15][k=quad*8+j].
// q-columns (tiles 0..3) pre-scaled by 0.125 (= 1/sqrt(64), exact pow2).
// ---------------------------------------------------------------------------
__global__ __launch_bounds__(256) void wprep_kernel(
    const float* __restrict__ Wq, const float* __restrict__ Wk,
    const float* __restrict__ Wv, unsigned short* __restrict__ wt2)
{
    const int f    = blockIdx.x * 256 + threadIdx.x;  // 0..24575
    const int nt   = f >> 11;
    const int kc   = (f >> 6) & 31;
    const int lane = f & 63;
    const int l15  = lane & 15, quad = lane >> 4;
    const int col  = nt * 16 + l15;                   // 0..191
    const float* W = (col < 64) ? Wq : ((col < 128) ? Wk : Wv);
    const int   cw = col & 63;
    const float sc = (col < 64) ? 0.125f : 1.0f;
    unsigned short o[8];
    #pragma unroll
    for (int j = 0; j < 8; j++) {
        const int kk = kc * 32 + quad * 8 + j;
        o[j] = f2bf(W[(size_t)kk * 64 + cw] * sc);
    }
    *(uint4*)&wt2[(size_t)f * 8] = *(const uint4*)o;
}

// ---------------------------------------------------------------------------
// Kernel 1: QKV projection, stall-free restructure.
// Grid 512 x 256 thr. Block = 32 rows x 192 cols.
// Phase A: stage the ENTIRE 32x1024 x-tile (128 KB f32) into 64 KB of LDS,
//   converted to bf16 and laid out in MFMA A-FRAGMENT order:
//     frag(c=0..15, ks=0..1, mt=0..1) at ((c*2+ks)*2+mt)*512 halfs,
//     element (lane, j): lane = kquad*16 + row15, j = k&7.
//   Staging is one long HBM stream with depth-2 reg pipeline; 8 waves/CU of
//   TLP keep HBM saturated. ONE barrier (was 16 lock-step barriers).
// Phase B: 16 barrier-free chunks: 4 sequential conflict-free ds_read_b128
//   (A frags, shared by all waves) + 6 L2 W loads (depth-1 prefetch) +
//   12 MFMA. No VALU in the hot loop (bf16 conversion already done).
// ---------------------------------------------------------------------------
__global__ __launch_bounds__(256) void qkv_kernel(
    const float* __restrict__ x, const unsigned short* __restrict__ wt2,
    unsigned short* __restrict__ qo, unsigned short* __restrict__ ko,
    unsigned short* __restrict__ vo)
{
    // 64 KB: frag-ordered x-tile; epilogue repack [32][200] aliases the front.
    __shared__ __align__(16) unsigned short smem[32768];

    const int t    = threadIdx.x;
    const int w    = t >> 6;
    const int lane = t & 63;
    const int l15  = lane & 15;
    const int quad = lane >> 4;
    const int r0   = blockIdx.x * 32;

    // ---- Phase A: stage x-tile into frag-ordered LDS ----
    {
        const int srow = t >> 3;            // 0..31
        const int g0   = t & 7;             // k-group 0..7 (+8i)
        const float* xrow = x + (size_t)(r0 + srow) * C_;
        const int mt_  = srow >> 4;
        const int r15_ = srow & 15;
        const int ks_  = (g0 >> 2) & 1;
        const int qd_  = g0 & 3;
        // lds half-offset for (c=i): ((i*2+ks_)*2+mt_)*512 + (qd_*16+r15_)*8
        unsigned short* dst = smem + (ks_ * 2 + mt_) * 512 + (qd_ * 16 + r15_) * 8;

        float4 cA0, cA1, cB0, cB1;
        cA0 = *(const float4*)(xrow + g0 * 8);
        cA1 = *(const float4*)(xrow + g0 * 8 + 4);
        #pragma unroll
        for (int i = 0; i < 16; i++) {
            if (i < 15) {
                cB0 = *(const float4*)(xrow + (i + 1) * 64 + g0 * 8);
                cB1 = *(const float4*)(xrow + (i + 1) * 64 + g0 * 8 + 4);
            }
            *(bf16x8*)(dst + i * 2048) = cvt8(cA0, cA1);
            cA0 = cB0; cA1 = cB1;
        }
    }
    __syncthreads();

    // ---- Phase B: barrier-free MFMA sweep over 16 k-chunks ----
    const unsigned short* wb = wt2 + (size_t)(w * 3) * 32 * 512 + lane * 8;

    floatx4 acc[2][3];
    #pragma unroll
    for (int mt = 0; mt < 2; mt++)
        #pragma unroll
        for (int nt = 0; nt < 3; nt++) acc[mt][nt] = (floatx4)(0.0f);

    bf16x8 wcur[6], wnxt[6];
    #pragma unroll
    for (int nt = 0; nt < 3; nt++)
        #pragma unroll
        for (int ks = 0; ks < 2; ks++)
            wcur[nt * 2 + ks] = *(const bf16x8*)(wb + (size_t)(nt * 32 + ks) * 512);

    #pragma unroll 2
    for (int c = 0; c < 16; c++) {
        if (c < 15) {
            #pragma unroll
            for (int nt = 0; nt < 3; nt++)
                #pragma unroll
                for (int ks = 0; ks < 2; ks++)
                    wnxt[nt * 2 + ks] = *(const bf16x8*)
                        (wb + (size_t)(nt * 32 + 2 * (c + 1) + ks) * 512);
        }
        #pragma unroll
        for (int ks = 0; ks < 2; ks++) {
            bf16x8 af[2];
            #pragma unroll
            for (int mt = 0; mt < 2; mt++)
                af[mt] = *(const bf16x8*)
                    (smem + ((c * 2 + ks) * 2 + mt) * 512 + lane * 8);
            #pragma unroll
            for (int mt = 0; mt < 2; mt++)
                #pragma unroll
                for (int nt = 0; nt < 3; nt++)
                    acc[mt][nt] = MFMA(af[mt], wcur[nt * 2 + ks], acc[mt][nt]);
        }
        if (c < 15) {
            #pragma unroll
            for (int i = 0; i < 6; i++) wcur[i] = wnxt[i];
        }
    }

    // ---- epilogue: repack through LDS (aliases frag region) ----
    __syncthreads();   // all waves done reading frags
    #pragma unroll
    for (int mt = 0; mt < 2; mt++)
        #pragma unroll
        for (int nt = 0; nt < 3; nt++) {
            const int col = w * 48 + nt * 16 + l15;
            #pragma unroll
            for (int r = 0; r < 4; r++)
                smem[(mt * 16 + quad * 4 + r) * 200 + col] = f2bf(acc[mt][nt][r]);
        }
    __syncthreads();

    { // q, k: [row][64] bf16 — 32 rows x 8 octs = 256 threads exactly
        const int row = t >> 3;
        const int oct = t & 7;
        *(uint4*)&qo[(size_t)(r0 + row) * 64 + oct * 8] =
            *(const uint4*)&smem[row * 200 + oct * 8];
        *(uint4*)&ko[(size_t)(r0 + row) * 64 + oct * 8] =
            *(const uint4*)&smem[row * 200 + 64 + oct * 8];
    }
    { // v: transposed [b][h][t]
        const int h = t >> 2, ts = (t & 3) * 8;
        const int bb = r0 >> 11, tt = r0 & 2047;
        unsigned short tmp[8];
        #pragma unroll
        for (int j = 0; j < 8; j++) tmp[j] = smem[(ts + j) * 200 + 128 + h];
        *(uint4*)&vo[((size_t)bb * 64 + h) * 2048 + tt + ts] = *(uint4*)&tmp[0];
    }
}

// ---------------------------------------------------------------------------
// Kernel 2: causal flash attention with ALiBi, bf16 MFMA.
// Occupancy/stall restructure vs previous version:
//  * 16-row q-tiles -> grid 1024 (4 q-tiles' worth of blocks per CU possible;
//    launch_bounds(256,3) -> 3 waves/SIMD instead of 2).
//  * kf double-buffer copy dropped: next-step K loaded straight into kf right
//    after QK^T consumed it (same overlap, -32 VGPR, no copy).
//  * pT row stride 72 -> 76 halfs: fixes 8-way bank conflict on the pf
//    ds_read_b128 (stride 144B put 8 lanes on the same 4-bank group).
// Softmax stays in log2 domain with row-shift folded out; causal mask only on
// the diagonal (last) step. K-range split 4 ways across waves; per-wave
// private softmax state + pT region, no per-step barriers.
// Grid 1024 = 8 batches x 128 q-tiles, heavy-first (pairs heavy+light on CU).
// ---------------------------------------------------------------------------
#define L2E 1.4426950408889634f
#define BS2 0.12751743f   // 2^-3.5 * log2(e) = alibi_slope * rsqrt(d) * log2e
#define PSTR 76           // pT row stride in halfs

__global__ __launch_bounds__(256, 3) void attn_kernel(
    const unsigned short* __restrict__ q,
    const unsigned short* __restrict__ k,
    const unsigned short* __restrict__ vT,
    float* __restrict__ out)
{
    // pT during loop: 4 waves x 16 x PSTR halfs = 9728 B at offset 0.
    // merge after barrier: Omg [4][16][64] f32 = 16384 B at 0,
    //                      mlg [4][2][16]  f32 =   512 B at 16384.
    __shared__ __align__(16) unsigned char smem[16384 + 512];
    unsigned short* pT  = (unsigned short*)smem;
    float*          Omg = (float*)smem;
    float*          mlg = (float*)(smem + 16384);

    const int t    = threadIdx.x;
    const int w    = t >> 6;
    const int lane = t & 63;
    const int l15  = lane & 15;
    const int quad = lane >> 4;
    const int b    = blockIdx.x & 7;
    const int qt   = 127 - (blockIdx.x >> 3);   // heavy tiles first
    const int q0   = qt * 16;
    const size_t kb = (size_t)b * T_ * 64;

    // Q A-fragments (1/sqrt(d) folded into Wq)
    bf16x8 qf[2];
    #pragma unroll
    for (int ks = 0; ks < 2; ks++)
        qf[ks] = *(const bf16x8*)
            &q[kb + (size_t)(q0 + l15) * 64 + ks * 32 + quad * 8];

    floatx4 O[4];
    float mrow[4], lrow[4];
    #pragma unroll
    for (int nt = 0; nt < 4; nt++) O[nt] = (floatx4)(0.0f);
    #pragma unroll
    for (int r = 0; r < 4; r++) { mrow[r] = -INFINITY; lrow[r] = 0.0f; }

    const int nsteps = (q0 + 16 + 63) >> 6;
    const int ns4    = (nsteps + 3) >> 2;
    const int sBeg   = w * ns4;
    const int sEnd   = min(sBeg + ns4, nsteps);
    unsigned short* pw = pT + w * 16 * PSTR;

    bf16x8 kf[4][2], vf[4][2];
    #define LOADK(dK, jj0)                                                     \
        { _Pragma("unroll")                                                    \
          for (int nt = 0; nt < 4; nt++)                                       \
              _Pragma("unroll")                                                \
              for (int ks = 0; ks < 2; ks++)                                   \
                  dK[nt][ks] = *(const bf16x8*)                                \
                      &k[kb + (size_t)((jj0) + nt*16 + l15)*64 + ks*32 + quad*8]; }
    #define LOADV(dV, jj0)                                                     \
        { _Pragma("unroll")                                                    \
          for (int nt = 0; nt < 4; nt++)                                       \
              _Pragma("unroll")                                                \
              for (int ks = 0; ks < 2; ks++)                                   \
                  dV[nt][ks] = *(const bf16x8*)                                \
                      &vT[((size_t)b*64 + nt*16 + l15)*2048 + (jj0) + ks*32 + quad*8]; }

    // softmax body; MASKED=true only on the diagonal step
    #define SMPART(MASKED)                                                     \
    {                                                                          \
        _Pragma("unroll")                                                      \
        for (int r = 0; r < 4; r++) {                                          \
            float xv[4];                                                       \
            _Pragma("unroll")                                                  \
            for (int nt = 0; nt < 4; nt++) {                                   \
                float v2 = fmaf(sc[nt][r], L2E, jn[nt]);                       \
                if (MASKED) {                                                  \
                    const int ig = q0 + quad * 4 + r;                          \
                    if (j0 + nt * 16 + l15 > ig) v2 = -INFINITY;               \
                }                                                              \
                xv[nt] = v2;                                                   \
            }                                                                  \
            float mloc = fmaxf(fmaxf(xv[0], xv[1]), fmaxf(xv[2], xv[3]));      \
            _Pragma("unroll")                                                  \
            for (int off = 1; off < 16; off <<= 1)                             \
                mloc = fmaxf(mloc, __shfl_xor(mloc, off));                     \
            const float mnew  = fmaxf(mrow[r], mloc);                          \
            const float alpha = fexp2(mrow[r] - mnew);                         \
            mrow[r] = mnew;                                                    \
            float ps = 0.0f;                                                   \
            _Pragma("unroll")                                                  \
            for (int nt = 0; nt < 4; nt++) {                                   \
                const float p = fexp2(xv[nt] - mnew);                          \
                ps += p;                                                       \
                pw[(quad * 4 + r) * PSTR + nt * 16 + l15] = f2bf_fast(p);      \
            }                                                                  \
            lrow[r] = lrow[r] * alpha + ps;                                    \
            _Pragma("unroll")                                                  \
            for (int nt = 0; nt < 4; nt++) O[nt][r] *= alpha;                  \
        }                                                                      \
    }

    if (sBeg < sEnd) LOADK(kf, sBeg * 64)

    for (int s = sBeg; s < sEnd; s++) {
        const int j0 = s * 64;

        // ---- S = Q K^T ----
        floatx4 sc[4];
        #pragma unroll
        for (int nt = 0; nt < 4; nt++) {
            floatx4 z = (floatx4)(0.0f);
            z = MFMA(qf[0], kf[nt][0], z);
            z = MFMA(qf[1], kf[nt][1], z);
            sc[nt] = z;
        }

        // ---- issue this step's V + next step's K (into kf, post-QK^T) ----
        LOADV(vf, j0)
        const bool more = (s + 1 < sEnd);
        if (more) LOADK(kf, (s + 1) * 64)

        // ---- ALiBi (log2 domain, row-shift folded out) + online softmax ----
        const float jb = (float)(j0 + l15) * BS2;
        const float jn[4] = { jb, jb + 16.0f * BS2, jb + 32.0f * BS2,
                              jb + 48.0f * BS2 };
        if (s != nsteps - 1) SMPART(false) else SMPART(true);

        // ---- O += P V  (same-wave DS in-order; no barrier) ----
        const bf16x8 pf0 = *(const bf16x8*)&pw[l15 * PSTR + quad * 8];
        const bf16x8 pf1 = *(const bf16x8*)&pw[l15 * PSTR + 32 + quad * 8];
        #pragma unroll
        for (int nt = 0; nt < 4; nt++) {
            O[nt] = MFMA(pf0, vf[nt][0], O[nt]);
            O[nt] = MFMA(pf1, vf[nt][1], O[nt]);
        }
    }
    #undef LOADK
    #undef LOADV
    #undef SMPART

    // ---- reduce per-lane l partials across the 16 key-lanes ----
    #pragma unroll
    for (int r = 0; r < 4; r++)
        #pragma unroll
        for (int off = 1; off < 16; off <<= 1)
            lrow[r] += __shfl_xor(lrow[r], off);

    __syncthreads();   // all waves done with pT

    // ---- publish partial state ----
    #pragma unroll
    for (int nt = 0; nt < 4; nt++)
        #pragma unroll
        for (int r = 0; r < 4; r++)
            Omg[w * 1024 + (quad * 4 + r) * 64 + nt * 16 + l15] = O[nt][r];
    if (l15 == 0) {
        #pragma unroll
        for (int r = 0; r < 4; r++) {
            mlg[w * 32 + quad * 4 + r]      = mrow[r];
            mlg[w * 32 + 16 + quad * 4 + r] = lrow[r];
        }
    }
    __syncthreads();

    // ---- merge 4 partials, write output (m in shifted log2 domain; the
    // shift is identical per row across waves, so it cancels here) ----
    {
        const int row = t >> 4;          // 0..15
        const int c4  = (t & 15) << 2;   // 0..60
        float mstar = -INFINITY;
        #pragma unroll
        for (int w2 = 0; w2 < 4; w2++)
            mstar = fmaxf(mstar, mlg[w2 * 32 + row]);
        floatx4 oa = (floatx4)(0.0f);
        float lsum = 0.0f;
        #pragma unroll
        for (int w2 = 0; w2 < 4; w2++) {
            const float wg = fexp2(mlg[w2 * 32 + row] - mstar);
            lsum += wg * mlg[w2 * 32 + 16 + row];
            oa += wg * *(const floatx4*)&Omg[w2 * 1024 + row * 64 + c4];
        }
        *(floatx4*)&out[kb + (size_t)(q0 + row) * 64 + c4] = oa * (1.0f / lsum);
    }
}

extern "C" void kernel_launch(void* const* d_in, const int* in_sizes, int n_in,
                              void* d_out, int out_size, void* d_ws, size_t ws_size,
                              hipStream_t stream) {
    (void)in_sizes; (void)n_in; (void)out_size; (void)ws_size;
    const float* x  = (const float*)d_in[0];
    const float* Wq = (const float*)d_in[1];
    const float* Wk = (const float*)d_in[2];
    const float* Wv = (const float*)d_in[3];
    float* out = (float*)d_out;

    unsigned short* wt2 = (unsigned short*)d_ws;                // [12][32][64][8]
    unsigned short* qw  = wt2 + 196608;                         // [M][64]
    unsigned short* kw  = qw + (size_t)M_ * H_;                 // [M][64]
    unsigned short* vw  = kw + (size_t)M_ * H_;                 // [B][64][2048]

    wprep_kernel<<<96, 256, 0, stream>>>(Wq, Wk, Wv, wt2);
    qkv_kernel<<<M_ / 32, 256, 0, stream>>>(x, wt2, qw, kw, vw);
    attn_kernel<<<B_ * 128, 256, 0, stream>>>(qw, kw, vw, out);
}

// Round 3
// 142.984 us; speedup vs baseline: 1.0030x; 1.0030x over previous
//
#include <hip/hip_runtime.h>
#include <hip/hip_bf16.h>
#include <math.h>

#define B_ 8
#define T_ 2048
#define C_ 1024
#define H_ 64
#define M_ (B_*T_)   // 16384 rows

typedef __attribute__((ext_vector_type(8))) short bf16x8;
typedef __attribute__((ext_vector_type(4))) float floatx4;

// fp32 -> bf16 round-to-nearest-even (cold paths)
static __device__ __forceinline__ unsigned short f2bf(float f) {
    union { float f; unsigned u; } v; v.f = f;
    unsigned r = v.u + 0x7fffu + ((v.u >> 16) & 1u);
    return (unsigned short)(r >> 16);
}
// pack two fp32 -> bf16 pair [hi|lo] in 3 VALU (add, add, v_perm)
static __device__ __forceinline__ unsigned pk2h(float lo, float hi) {
    union { float f; unsigned u; } a, b; a.f = lo; b.f = hi;
    return __builtin_amdgcn_perm(b.u + 0x8000u, a.u + 0x8000u, 0x07060302u);
}
static __device__ __forceinline__ bf16x8 cvt8(float4 f0, float4 f1) {
    union { uint4 u; bf16x8 v; } r;
    r.u.x = pk2h(f0.x, f0.y); r.u.y = pk2h(f0.z, f0.w);
    r.u.z = pk2h(f1.x, f1.y); r.u.w = pk2h(f1.z, f1.w);
    return r.v;
}
// 2^x
static __device__ __forceinline__ float fexp2(float x) {
#if defined(__has_builtin)
#if __has_builtin(__builtin_amdgcn_exp2f)
    return __builtin_amdgcn_exp2f(x);
#else
    return exp2f(x);
#endif
#else
    return exp2f(x);
#endif
}

#define MFMA(a,b,c) __builtin_amdgcn_mfma_f32_16x16x32_bf16((a),(b),(c),0,0,0)

// ---------------------------------------------------------------------------
// Kernel 0: W prep -> wt2 in MFMA B-fragment order (unchanged).
// wt2 flat: ((tile*32 + kchunk)*64 + lane)*8; tile=0..11 (16 cols, q|k|v),
// kchunk=0..31 (32 k each); lane frag [col=l15][k=quad*8+j].
// q-columns (tiles 0..3) pre-scaled by 0.125 (= 1/sqrt(64), exact pow2).
// ---------------------------------------------------------------------------
__global__ __launch_bounds__(256) void wprep_kernel(
    const float* __restrict__ Wq, const float* __restrict__ Wk,
    const float* __restrict__ Wv, unsigned short* __restrict__ wt2)
{
    const int f    = blockIdx.x * 256 + threadIdx.x;  // 0..24575
    const int nt   = f >> 11;
    const int kc   = (f >> 6) & 31;
    const int lane = f & 63;
    const int l15  = lane & 15, quad = lane >> 4;
    const int col  = nt * 16 + l15;                   // 0..191
    const float* W = (col < 64) ? Wq : ((col < 128) ? Wk : Wv);
    const int   cw = col & 63;
    const float sc = (col < 64) ? 0.125f : 1.0f;
    unsigned short o[8];
    #pragma unroll
    for (int j = 0; j < 8; j++) {
        const int kk = kc * 32 + quad * 8 + j;
        o[j] = f2bf(W[(size_t)kk * 64 + cw] * sc);
    }
    *(uint4*)&wt2[(size_t)f * 8] = *(const uint4*)o;
}

// ---------------------------------------------------------------------------
// Kernel 1: QKV projection. Grid 512 x 256 thr. Block = 32 rows x 192 cols.
// Phase A: stage the ENTIRE 32x1024 x-tile into 64 KB LDS in MFMA A-fragment
//   order, with a DEPTH-4 rolling register prefetch (was depth-2): ~3x less
//   exposed HBM latency per staging iteration. ONE barrier.
// Phase B: 16 barrier-free chunks: 4 contiguous conflict-free ds_read_b128 +
//   6 L2 W-loads (depth-1 prefetch) + 12 MFMA. No VALU in hot loop.
// ---------------------------------------------------------------------------
__global__ __launch_bounds__(256) void qkv_kernel(
    const float* __restrict__ x, const unsigned short* __restrict__ wt2,
    unsigned short* __restrict__ qo, unsigned short* __restrict__ ko,
    unsigned short* __restrict__ vo)
{
    // 64 KB: frag-ordered x-tile; epilogue repack [32][200] aliases the front.
    __shared__ __align__(16) unsigned short smem[32768];

    const int t    = threadIdx.x;
    const int w    = t >> 6;
    const int lane = t & 63;
    const int l15  = lane & 15;
    const int quad = lane >> 4;
    const int r0   = blockIdx.x * 32;

    // ---- Phase A: stage x-tile into frag-ordered LDS (depth-4 prefetch) ----
    {
        const int srow = t >> 3;            // 0..31
        const int g0   = t & 7;             // k-group 0..7 (+8i)
        const float* xrow = x + (size_t)(r0 + srow) * C_;
        const int mt_  = srow >> 4;
        const int r15_ = srow & 15;
        const int ks_  = (g0 >> 2) & 1;
        const int qd_  = g0 & 3;
        // lds half-offset for chunk i: ((i*2+ks_)*2+mt_)*512 + (qd_*16+r15_)*8
        unsigned short* dst = smem + (ks_ * 2 + mt_) * 512 + (qd_ * 16 + r15_) * 8;

        float4 cb[4][2];
        #pragma unroll
        for (int i = 0; i < 3; i++) {
            cb[i][0] = *(const float4*)(xrow + i * 64 + g0 * 8);
            cb[i][1] = *(const float4*)(xrow + i * 64 + g0 * 8 + 4);
        }
        #pragma unroll
        for (int i = 0; i < 16; i++) {
            if (i < 13) {
                cb[(i + 3) & 3][0] = *(const float4*)(xrow + (i + 3) * 64 + g0 * 8);
                cb[(i + 3) & 3][1] = *(const float4*)(xrow + (i + 3) * 64 + g0 * 8 + 4);
            }
            *(bf16x8*)(dst + i * 2048) = cvt8(cb[i & 3][0], cb[i & 3][1]);
        }
    }
    __syncthreads();

    // ---- Phase B: barrier-free MFMA sweep over 16 k-chunks ----
    const unsigned short* wb = wt2 + (size_t)(w * 3) * 32 * 512 + lane * 8;

    floatx4 acc[2][3];
    #pragma unroll
    for (int mt = 0; mt < 2; mt++)
        #pragma unroll
        for (int nt = 0; nt < 3; nt++) acc[mt][nt] = (floatx4)(0.0f);

    bf16x8 wcur[6], wnxt[6];
    #pragma unroll
    for (int nt = 0; nt < 3; nt++)
        #pragma unroll
        for (int ks = 0; ks < 2; ks++)
            wcur[nt * 2 + ks] = *(const bf16x8*)(wb + (size_t)(nt * 32 + ks) * 512);

    #pragma unroll 2
    for (int c = 0; c < 16; c++) {
        if (c < 15) {
            #pragma unroll
            for (int nt = 0; nt < 3; nt++)
                #pragma unroll
                for (int ks = 0; ks < 2; ks++)
                    wnxt[nt * 2 + ks] = *(const bf16x8*)
                        (wb + (size_t)(nt * 32 + 2 * (c + 1) + ks) * 512);
        }
        #pragma unroll
        for (int ks = 0; ks < 2; ks++) {
            bf16x8 af[2];
            #pragma unroll
            for (int mt = 0; mt < 2; mt++)
                af[mt] = *(const bf16x8*)
                    (smem + ((c * 2 + ks) * 2 + mt) * 512 + lane * 8);
            #pragma unroll
            for (int mt = 0; mt < 2; mt++)
                #pragma unroll
                for (int nt = 0; nt < 3; nt++)
                    acc[mt][nt] = MFMA(af[mt], wcur[nt * 2 + ks], acc[mt][nt]);
        }
        if (c < 15) {
            #pragma unroll
            for (int i = 0; i < 6; i++) wcur[i] = wnxt[i];
        }
    }

    // ---- epilogue: repack through LDS (aliases frag region) ----
    __syncthreads();   // all waves done reading frags
    #pragma unroll
    for (int mt = 0; mt < 2; mt++)
        #pragma unroll
        for (int nt = 0; nt < 3; nt++) {
            const int col = w * 48 + nt * 16 + l15;
            #pragma unroll
            for (int r = 0; r < 4; r++)
                smem[(mt * 16 + quad * 4 + r) * 200 + col] = f2bf(acc[mt][nt][r]);
        }
    __syncthreads();

    { // q, k: [row][64] bf16 — 32 rows x 8 octs = 256 threads exactly
        const int row = t >> 3;
        const int oct = t & 7;
        *(uint4*)&qo[(size_t)(r0 + row) * 64 + oct * 8] =
            *(const uint4*)&smem[row * 200 + oct * 8];
        *(uint4*)&ko[(size_t)(r0 + row) * 64 + oct * 8] =
            *(const uint4*)&smem[row * 200 + 64 + oct * 8];
    }
    { // v: transposed [b][h][t]
        const int h = t >> 2, ts = (t & 3) * 8;
        const int bb = r0 >> 11, tt = r0 & 2047;
        unsigned short tmp[8];
        #pragma unroll
        for (int j = 0; j < 8; j++) tmp[j] = smem[(ts + j) * 200 + 128 + h];
        *(uint4*)&vo[((size_t)bb * 64 + h) * 2048 + tt + ts] = *(uint4*)&tmp[0];
    }
}

// ---------------------------------------------------------------------------
// Kernel 2: causal flash attention with ALiBi, bf16 MFMA — SWAPPED QK^T.
// S^T = MFMA(K, Q): each lane holds 16 scores of ONE q-row (q = l15), so:
//  * row max = 15-op in-register tree + 2 shfl_xor (was 16 shfl + 12 max);
//  * alpha = ONE exp per lane (was 4); l is a per-lane partial, reduced once
//    after the loop;
//  * P written as 4x ds_write_b64 (pk2h pairs) instead of 16x ds_write_b16;
//    PV A-fragment read unchanged (contiguous ds_read_b128 from [q][k] pT).
//  * ALiBi: per-lane loop-invariant bconst regs + per-step uniform shift j0b
//    folded into the running max (softmax shift-invariance).
//  * s_setprio(1) around MFMA clusters.
// 16-row q-tiles, grid 1024 = 8 batches x 128 tiles heavy-first, 4-wave
// K-split, per-wave private state, no per-step barriers, K depth-1 prefetch.
// ---------------------------------------------------------------------------
#define L2E 1.4426950408889634f
#define BS2 0.12751743f   // 2^-3.5 * log2(e) = alibi_slope * rsqrt(d) * log2e
#define PSTR 72           // pT row stride in halfs

__global__ __launch_bounds__(256, 3) void attn_kernel(
    const unsigned short* __restrict__ q,
    const unsigned short* __restrict__ k,
    const unsigned short* __restrict__ vT,
    float* __restrict__ out)
{
    // pT during loop: 4 waves x 16 x PSTR halfs = 9216 B at offset 0.
    // merge after barrier: Omg [4][16][64] f32 = 16384 B at 0,
    //                      mlg [4][2][16]  f32 =   512 B at 16384.
    __shared__ __align__(16) unsigned char smem[16384 + 512];
    unsigned short* pT  = (unsigned short*)smem;
    float*          Omg = (float*)smem;
    float*          mlg = (float*)(smem + 16384);

    const int t    = threadIdx.x;
    const int w    = t >> 6;
    const int lane = t & 63;
    const int l15  = lane & 15;
    const int quad = lane >> 4;
    const int b    = blockIdx.x & 7;
    const int qt   = 127 - (blockIdx.x >> 3);   // heavy tiles first
    const int q0   = qt * 16;
    const size_t kb = (size_t)b * T_ * 64;

    // Q fragments (used as MFMA B operand; same lane layout as A). 1/sqrt(d)
    // is folded into Wq.
    bf16x8 qf[2];
    #pragma unroll
    for (int ks = 0; ks < 2; ks++)
        qf[ks] = *(const bf16x8*)
            &q[kb + (size_t)(q0 + l15) * 64 + ks * 32 + quad * 8];

    floatx4 O[4];
    #pragma unroll
    for (int nt = 0; nt < 4; nt++) O[nt] = (floatx4)(0.0f);
    float mrow = -INFINITY, lrow = 0.0f;   // per-lane; q = l15, k-partial

    // loop-invariant per-lane ALiBi constants: (nt*16 + quad*4 + r) * BS2
    float bconst[4][4];
    #pragma unroll
    for (int nt = 0; nt < 4; nt++)
        #pragma unroll
        for (int r = 0; r < 4; r++)
            bconst[nt][r] = (float)(nt * 16 + quad * 4 + r) * BS2;

    const int nsteps = (q0 + 16 + 63) >> 6;
    const int ns4    = (nsteps + 3) >> 2;
    const int sBeg   = w * ns4;
    const int sEnd   = min(sBeg + ns4, nsteps);
    unsigned short* pw = pT + w * 16 * PSTR;

    bf16x8 kf[4][2], vf[4][2];
    #define LOADK(dK, jj0)                                                     \
        { _Pragma("unroll")                                                    \
          for (int nt = 0; nt < 4; nt++)                                       \
              _Pragma("unroll")                                                \
              for (int ks = 0; ks < 2; ks++)                                   \
                  dK[nt][ks] = *(const bf16x8*)                                \
                      &k[kb + (size_t)((jj0) + nt*16 + l15)*64 + ks*32 + quad*8]; }
    #define LOADV(dV, jj0)                                                     \
        { _Pragma("unroll")                                                    \
          for (int nt = 0; nt < 4; nt++)                                       \
              _Pragma("unroll")                                                \
              for (int ks = 0; ks < 2; ks++)                                   \
                  dV[nt][ks] = *(const bf16x8*)                                \
                      &vT[((size_t)b*64 + nt*16 + l15)*2048 + (jj0) + ks*32 + quad*8]; }

    // softmax body (swapped layout); MASKED=true only on the diagonal step
    #define SMPART(MASKED)                                                     \
    {                                                                          \
        float xv[4][4];                                                        \
        const int qk2 = q0 + l15 - j0 - quad * 4;                              \
        _Pragma("unroll")                                                      \
        for (int nt = 0; nt < 4; nt++)                                         \
            _Pragma("unroll")                                                  \
            for (int r = 0; r < 4; r++) {                                      \
                float v2 = fmaf(sc[nt][r], L2E, bconst[nt][r]);                \
                if (MASKED) { if (nt * 16 + r > qk2) v2 = -INFINITY; }         \
                xv[nt][r] = v2;                                                \
            }                                                                  \
        /* 16-value in-register max tree */                                    \
        float m01 = fmaxf(fmaxf(xv[0][0], xv[0][1]), fmaxf(xv[0][2], xv[0][3]));\
        float m11 = fmaxf(fmaxf(xv[1][0], xv[1][1]), fmaxf(xv[1][2], xv[1][3]));\
        float m21 = fmaxf(fmaxf(xv[2][0], xv[2][1]), fmaxf(xv[2][2], xv[2][3]));\
        float m31 = fmaxf(fmaxf(xv[3][0], xv[3][1]), fmaxf(xv[3][2], xv[3][3]));\
        float mloc = fmaxf(fmaxf(m01, m11), fmaxf(m21, m31));                  \
        /* cross-quad (same q-row) reduce: lanes l15, l15+16, +32, +48 */      \
        mloc = fmaxf(mloc, __shfl_xor(mloc, 16));                              \
        mloc = fmaxf(mloc, __shfl_xor(mloc, 32));                              \
        const float mnew  = fmaxf(mrow, mloc + j0b);                           \
        const float alpha = fexp2(mrow - mnew);                                \
        mrow = mnew;                                                           \
        const float msub = mnew - j0b;                                         \
        float ps = 0.0f;                                                       \
        _Pragma("unroll")                                                      \
        for (int nt = 0; nt < 4; nt++) {                                       \
            const float p0 = fexp2(xv[nt][0] - msub);                          \
            const float p1 = fexp2(xv[nt][1] - msub);                          \
            const float p2 = fexp2(xv[nt][2] - msub);                          \
            const float p3 = fexp2(xv[nt][3] - msub);                          \
            ps += (p0 + p1) + (p2 + p3);                                       \
            union { unsigned u[2]; uint2 v; } pk;                              \
            pk.u[0] = pk2h(p0, p1); pk.u[1] = pk2h(p2, p3);                    \
            *(uint2*)&pw[l15 * PSTR + nt * 16 + quad * 4] = pk.v;              \
        }                                                                      \
        lrow = lrow * alpha + ps;                                              \
        /* transpose alpha to O orientation (q = quad*4+r) */                  \
        float aT[4];                                                           \
        _Pragma("unroll")                                                      \
        for (int r = 0; r < 4; r++) aT[r] = __shfl(alpha, (quad << 2) + r);    \
        _Pragma("unroll")                                                      \
        for (int nt = 0; nt < 4; nt++)                                         \
            _Pragma("unroll")                                                  \
            for (int r = 0; r < 4; r++) O[nt][r] *= aT[r];                     \
    }

    if (sBeg < sEnd) LOADK(kf, sBeg * 64)

    for (int s = sBeg; s < sEnd; s++) {
        const int j0 = s * 64;
        const float j0b = (float)j0 * BS2;

        // ---- S^T = K Q^T : lane holds q-col l15, k-rows quad*4+r (+nt*16) --
        floatx4 sc[4];
        __builtin_amdgcn_s_setprio(1);
        #pragma unroll
        for (int nt = 0; nt < 4; nt++) {
            floatx4 z = (floatx4)(0.0f);
            z = MFMA(kf[nt][0], qf[0], z);
            z = MFMA(kf[nt][1], qf[1], z);
            sc[nt] = z;
        }
        __builtin_amdgcn_s_setprio(0);

        // ---- issue this step's V + next step's K (into kf, post-QK^T) ----
        LOADV(vf, j0)
        const bool more = (s + 1 < sEnd);
        if (more) LOADK(kf, (s + 1) * 64)

        // ---- online softmax in swapped layout ----
        if (s != nsteps - 1) SMPART(false) else SMPART(true);

        // ---- O += P V  (same-wave DS in-order; no barrier) ----
        const bf16x8 pf0 = *(const bf16x8*)&pw[l15 * PSTR + quad * 8];
        const bf16x8 pf1 = *(const bf16x8*)&pw[l15 * PSTR + 32 + quad * 8];
        __builtin_amdgcn_s_setprio(1);
        #pragma unroll
        for (int nt = 0; nt < 4; nt++) {
            O[nt] = MFMA(pf0, vf[nt][0], O[nt]);
            O[nt] = MFMA(pf1, vf[nt][1], O[nt]);
        }
        __builtin_amdgcn_s_setprio(0);
    }
    #undef LOADK
    #undef LOADV
    #undef SMPART

    // ---- finalize per-lane l partials across the 4 quad-lanes of each row --
    lrow += __shfl_xor(lrow, 16);
    lrow += __shfl_xor(lrow, 32);

    __syncthreads();   // all waves done with pT

    // ---- publish partial state ----
    #pragma unroll
    for (int nt = 0; nt < 4; nt++)
        #pragma unroll
        for (int r = 0; r < 4; r++)
            Omg[w * 1024 + (quad * 4 + r) * 64 + nt * 16 + l15] = O[nt][r];
    if (quad == 0) {
        mlg[w * 32 + l15]      = mrow;
        mlg[w * 32 + 16 + l15] = lrow;
    }
    __syncthreads();

    // ---- merge 4 partials, write output ----
    {
        const int row = t >> 4;          // 0..15
        const int c4  = (t & 15) << 2;   // 0..60
        float mstar = -INFINITY;
        #pragma unroll
        for (int w2 = 0; w2 < 4; w2++)
            mstar = fmaxf(mstar, mlg[w2 * 32 + row]);
        floatx4 oa = (floatx4)(0.0f);
        float lsum = 0.0f;
        #pragma unroll
        for (int w2 = 0; w2 < 4; w2++) {
            const float wg = fexp2(mlg[w2 * 32 + row] - mstar);
            lsum += wg * mlg[w2 * 32 + 16 + row];
            oa += wg * *(const floatx4*)&Omg[w2 * 1024 + row * 64 + c4];
        }
        *(floatx4*)&out[kb + (size_t)(q0 + row) * 64 + c4] = oa * (1.0f / lsum);
    }
}

extern "C" void kernel_launch(void* const* d_in, const int* in_sizes, int n_in,
                              void* d_out, int out_size, void* d_ws, size_t ws_size,
                              hipStream_t stream) {
    (void)in_sizes; (void)n_in; (void)out_size; (void)ws_size;
    const float* x  = (const float*)d_in[0];
    const float* Wq = (const float*)d_in[1];
    const float* Wk = (const float*)d_in[2];
    const float* Wv = (const float*)d_in[3];
    float* out = (float*)d_out;

    unsigned short* wt2 = (unsigned short*)d_ws;                // [12][32][64][8]
    unsigned short* qw  = wt2 + 196608;                         // [M][64]
    unsigned short* kw  = qw + (size_t)M_ * H_;                 // [M][64]
    unsigned short* vw  = kw + (size_t)M_ * H_;                 // [B][64][2048]

    wprep_kernel<<<96, 256, 0, stream>>>(Wq, Wk, Wv, wt2);
    qkv_kernel<<<M_ / 32, 256, 0, stream>>>(x, wt2, qw, kw, vw);
    attn_kernel<<<B_ * 128, 256, 0, stream>>>(qw, kw, vw, out);
}